// Round 10
// baseline (77.377 us; speedup 1.0000x reference)
//
#include <hip/hip_runtime.h>
#include <math.h>

#define NT 50
#define NC 20
#define NB 64
#define NCORR 192                  // 3 scales x 64 batches, dispatched FIRST
#define CHUNK 2048                 // float4 per stream block (8 per thread)
#define NS0 1585                   // ceil(3244800/2048)
#define NS1 397                    // ceil(811200/2048)
#define NS2 100                    // ceil(202800/2048)
#define NSTREAM (NS0 + NS1 + NS2)  // 2082
#define NBLK (NCORR + NSTREAM)     // 2274 = 71*32 + 2
#define CNT_OFF 16384              // byte offset of counters inside ws

// anchors / stride per scale: scale0 fs=52 (masks 6,7,8), scale1 fs=26, scale2 fs=13
__device__ __constant__ float c_aw[3][3] = {
    {14.5f, 19.5f, 46.625f},
    {1.875f, 3.875f, 3.6875f},
    {0.3125f, 0.5f, 1.03125f}};
__device__ __constant__ float c_ah[3][3] = {
    {11.25f, 24.75f, 40.75f},
    {3.8125f, 2.8125f, 7.4375f},
    {0.40625f, 0.9375f, 0.71875f}};
// 1/(NB*cells) per scale: cells = 8112, 2028, 507
__device__ __constant__ float c_invN[3] = {
    1.0f / 519168.0f, 1.0f / 129792.0f, 1.0f / 32448.0f};

__device__ __forceinline__ float softplus_f(float x) {
  return __logf(1.0f + __expf(x));  // -log(1-sigmoid(x)) == softplus(x)
}
__device__ __forceinline__ float sigmoid_f(float x) {
  return 1.0f / (1.0f + __expf(-x));
}

__global__ __launch_bounds__(256) void yolo_main(
    const float* __restrict__ pred0, const float* __restrict__ pred1,
    const float* __restrict__ pred2, const float* __restrict__ boxes,
    const int* __restrict__ cls, float* __restrict__ ws, int* __restrict__ cnt,
    float* __restrict__ out) {
  const int bid = blockIdx.x;
  const int tid = threadIdx.x;
  __shared__ float s_red[4];
  __shared__ int s_fin;
  float acc = 0.0f;

  if (bid >= NCORR) {
    // ---------------- STREAM: every element treated as noobj ----------------
    // Only channel f%25==4 (conf) contributes: 0.5*invN*softplus(v).
    int sb = bid - NCORR;
    int scale, part, nf4;
    const float* arr;
    if (sb < NS0) { scale = 0; part = sb; arr = pred0; nf4 = 3244800; }
    else if (sb < NS0 + NS1) { scale = 1; part = sb - NS0; arr = pred1; nf4 = 811200; }
    else { scale = 2; part = sb - NS0 - NS1; arr = pred2; nf4 = 202800; }
    const float4* p4 = (const float4*)arr;
    const int base = part * CHUNK;
    const int i0 = base + tid;
    int ch = (i0 << 2) % 25;  // channel of component .x; advance -1 mod 25 per 256 f4
    if (base + CHUNK <= nf4) {
      // full chunk: 8 independent loads in flight per thread
#pragma unroll
      for (int k = 0; k < 8; ++k) {
        float4 v = p4[i0 + k * 256];
        float vc = (ch == 4) ? v.x : ((ch == 3) ? v.y : ((ch == 2) ? v.z : v.w));
        acc += (ch >= 1 && ch <= 4) ? softplus_f(vc) : 0.0f;
        ch = (ch >= 1) ? (ch - 1) : 24;
      }
    } else {
      for (int i = i0; i < nf4; i += 256) {
        float4 v = p4[i];
        float vc = (ch == 4) ? v.x : ((ch == 3) ? v.y : ((ch == 2) ? v.z : v.w));
        acc += (ch >= 1 && ch <= 4) ? softplus_f(vc) : 0.0f;
        ch = (ch >= 1) ? (ch - 1) : 24;
      }
    }
    acc *= c_invN[scale] * (0.5f / 3.0f);
  } else {
    // -------------- CORRECTION: exact obj-cell terms, minus over-count -----
    const int scale = bid >> 6;  // 0..2
    const int b = bid & 63;
    const int fs = (scale == 0) ? 52 : ((scale == 1) ? 26 : 13);
    const int cells = fs * fs * 3;
    const float* arr = (scale == 0) ? pred0 : ((scale == 1) ? pred1 : pred2);
    const float* plane = arr + (size_t)b * cells * 25;
    const float invN = c_invN[scale];
    const float invNC = invN * (1.0f / (float)NC);

    __shared__ int s_cell[NT];
    __shared__ unsigned s_bit[NT];

    int cell = -1, gx = 0, gy = 0, best = 0;
    float tcx = 0.f, tcy = 0.f, tww = 0.f, thh = 0.f;
    if (tid < NT) {
      const float* bx = boxes + ((size_t)b * NT + tid) * 4;
      float ffs = (float)fs;
      float tbx = bx[0] * ffs;
      float tby = bx[1] * ffs;
      float tw = bx[2] * ffs;
      float th = bx[3] * ffs;
      float bestr = -1.0f;
      for (int a = 0; a < 3; ++a) {
        float aw = c_aw[scale][a], ah = c_ah[scale][a];
        float inter = fminf(tw, aw) * fminf(th, ah);
        float uni = tw * th + aw * ah - inter;
        float rr = inter / (uni + 1e-6f);
        if (rr > bestr) { bestr = rr; best = a; }
      }
      gx = (int)tbx;
      if (gx < 0) gx = 0;
      if (gx > fs - 1) gx = fs - 1;
      gy = (int)tby;
      if (gy < 0) gy = 0;
      if (gy > fs - 1) gy = fs - 1;
      cell = (gy * fs + gx) * 3 + best;
      tcx = tbx - (float)gx;
      tcy = tby - (float)gy;
      tww = __logf(tw / c_aw[scale][best] + 1e-6f);
      thh = __logf(th / c_ah[scale][best] + 1e-6f);
      s_cell[tid] = cell;
      s_bit[tid] = 1u << cls[(size_t)b * NT + tid];
    }
    __syncthreads();
    if (tid < NT) {
      // last target with my cell wins; class bits union over all matches
      int win = -1;
      unsigned mask = 0u;
      for (int t = 0; t < NT; ++t)
        if (s_cell[t] == cell) { win = t; mask |= s_bit[t]; }
      if (win == tid) {
        const float* p = plane + cell * 25;
        float aw = c_aw[scale][best], ah = c_ah[scale][best];
        float d0 = sigmoid_f(p[0]) + (float)gx - tcx;
        float d1 = sigmoid_f(p[1]) + (float)gy - tcy;
        float d2 = __expf(p[2]) * aw - tww;
        float d3 = __expf(p[3]) * ah - thh;
        float coord = 5.0f * invN * (d0 * d0 + d1 * d1 + d2 * d2 + d3 * d3);
        float v4 = p[4];
        // add obj conf term, remove the noobj term the stream counted
        float conf = invN * softplus_f(-v4) - 0.5f * invN * softplus_f(v4);
        float csum = 0.0f;
        for (int c = 0; c < NC; ++c) {
          float v = p[5 + c];
          csum += ((mask >> c) & 1u) ? softplus_f(-v) : softplus_f(v);
        }
        acc = (coord + conf + csum * invNC) * (1.0f / 3.0f);
      }
    }
  }

  // ---- block reduction -> per-block partial ----
  for (int off = 32; off > 0; off >>= 1) acc += __shfl_down(acc, off);
  if ((tid & 63) == 0) s_red[tid >> 6] = acc;
  __syncthreads();

  // ---- completion protocol: two-level counters, last block reduces ----
  if (tid == 0) {
    ws[bid] = s_red[0] + s_red[1] + s_red[2] + s_red[3];
    __threadfence();  // partial visible device-wide before counting
    const int line = bid & 31;
    const int quota = 71 + (line < (NBLK & 31) ? 1 : 0);  // 2274 = 71*32 + 2
    int fin = 0;
    int old = atomicAdd(&cnt[line * 16], 1);  // 64B-spaced counter lines
    if (old == quota - 1) {
      int old2 = atomicAdd(&cnt[32 * 16], 1);
      if (old2 == 31) fin = 1;
    }
    s_fin = fin;
  }
  __syncthreads();

  if (s_fin) {
    __threadfence();
    float v = 0.0f;
#pragma unroll
    for (int k = 0; k < 9; ++k) {
      int i = tid + k * 256;
      if (i < NBLK)
        v += __hip_atomic_load(&ws[i], __ATOMIC_RELAXED, __HIP_MEMORY_SCOPE_AGENT);
    }
    for (int off = 32; off > 0; off >>= 1) v += __shfl_down(v, off);
    if ((tid & 63) == 0) s_red[tid >> 6] = v;
    __syncthreads();
    if (tid == 0) out[0] = s_red[0] + s_red[1] + s_red[2] + s_red[3];
  }
}

extern "C" void kernel_launch(void* const* d_in, const int* in_sizes, int n_in,
                              void* d_out, int out_size, void* d_ws, size_t ws_size,
                              hipStream_t stream) {
  const float* pred0 = (const float*)d_in[0];
  const float* pred1 = (const float*)d_in[1];
  const float* pred2 = (const float*)d_in[2];
  const float* boxes = (const float*)d_in[3];
  const int* cls = (const int*)d_in[4];
  float* out = (float*)d_out;
  float* ws = (float*)d_ws;
  int* cnt = (int*)((char*)d_ws + CNT_OFF);

  // reset completion counters (graph memset node, replayed each iteration)
  hipMemsetAsync((void*)cnt, 0, 33 * 64, stream);
  yolo_main<<<NBLK, 256, 0, stream>>>(pred0, pred1, pred2, boxes, cls, ws, cnt, out);
}

// Round 11
// 38.452 us; speedup vs baseline: 2.0123x; 2.0123x over previous
//
#include <hip/hip_runtime.h>
#include <math.h>

#define NT 50
#define NC 20
#define NB 64
#define NCORR 192                  // 3 scales x 64 batches, dispatched FIRST
#define CHUNK 2048                 // float4 per stream block (8 per thread)
#define NS0 1585                   // ceil(3244800/2048)
#define NS1 397                    // ceil(811200/2048)
#define NS2 100                    // ceil(202800/2048)
#define NSTREAM (NS0 + NS1 + NS2)  // 2082
#define NBLK (NCORR + NSTREAM)     // 2274

// anchors / stride per scale: scale0 fs=52 (masks 6,7,8), scale1 fs=26, scale2 fs=13
__device__ __constant__ float c_aw[3][3] = {
    {14.5f, 19.5f, 46.625f},
    {1.875f, 3.875f, 3.6875f},
    {0.3125f, 0.5f, 1.03125f}};
__device__ __constant__ float c_ah[3][3] = {
    {11.25f, 24.75f, 40.75f},
    {3.8125f, 2.8125f, 7.4375f},
    {0.40625f, 0.9375f, 0.71875f}};
// 1/(NB*cells) per scale: cells = 8112, 2028, 507
__device__ __constant__ float c_invN[3] = {
    1.0f / 519168.0f, 1.0f / 129792.0f, 1.0f / 32448.0f};

__device__ __forceinline__ float softplus_f(float x) {
  return __logf(1.0f + __expf(x));  // -log(1-sigmoid(x)) == softplus(x)
}
__device__ __forceinline__ float sigmoid_f(float x) {
  return 1.0f / (1.0f + __expf(-x));
}

__global__ __launch_bounds__(256) void yolo_main(
    const float* __restrict__ pred0, const float* __restrict__ pred1,
    const float* __restrict__ pred2, const float* __restrict__ boxes,
    const int* __restrict__ cls, float* __restrict__ ws) {
  const int bid = blockIdx.x;
  const int tid = threadIdx.x;
  __shared__ float s_red[4];
  float acc = 0.0f;

  if (bid >= NCORR) {
    // ---------------- STREAM: every element treated as noobj ----------------
    // Only channel f%25==4 (conf) contributes: 0.5*invN*softplus(v).
    int sb = bid - NCORR;
    int scale, part, nf4;
    const float* arr;
    if (sb < NS0) { scale = 0; part = sb; arr = pred0; nf4 = 3244800; }
    else if (sb < NS0 + NS1) { scale = 1; part = sb - NS0; arr = pred1; nf4 = 811200; }
    else { scale = 2; part = sb - NS0 - NS1; arr = pred2; nf4 = 202800; }
    const float4* p4 = (const float4*)arr;
    const int base = part * CHUNK;
    const int i0 = base + tid;
    int ch = (i0 << 2) % 25;  // channel of component .x; advance -1 mod 25 per 256 f4
    if (base + CHUNK <= nf4) {
      // load phase: 8 f4 in registers -> 8 global_load_dwordx4 in flight
      float4 v[8];
#pragma unroll
      for (int k = 0; k < 8; ++k) v[k] = p4[i0 + k * 256];
      // compute phase (static indices only)
#pragma unroll
      for (int k = 0; k < 8; ++k) {
        float vc = (ch == 4) ? v[k].x
                             : ((ch == 3) ? v[k].y : ((ch == 2) ? v[k].z : v[k].w));
        acc += (ch >= 1 && ch <= 4) ? softplus_f(vc) : 0.0f;
        ch = (ch >= 1) ? (ch - 1) : 24;
      }
    } else {
      for (int i = i0; i < nf4; i += 256) {
        float4 v = p4[i];
        float vc = (ch == 4) ? v.x : ((ch == 3) ? v.y : ((ch == 2) ? v.z : v.w));
        acc += (ch >= 1 && ch <= 4) ? softplus_f(vc) : 0.0f;
        ch = (ch >= 1) ? (ch - 1) : 24;
      }
    }
    acc *= c_invN[scale] * (0.5f / 3.0f);
  } else {
    // -------------- CORRECTION: exact obj-cell terms, minus over-count -----
    const int scale = bid >> 6;  // 0..2
    const int b = bid & 63;
    const int fs = (scale == 0) ? 52 : ((scale == 1) ? 26 : 13);
    const int cells = fs * fs * 3;
    const float* arr = (scale == 0) ? pred0 : ((scale == 1) ? pred1 : pred2);
    const float* plane = arr + (size_t)b * cells * 25;
    const float invN = c_invN[scale];
    const float invNC = invN * (1.0f / (float)NC);

    __shared__ int s_cell[NT];
    __shared__ unsigned s_bit[NT];

    int cell = -1, gx = 0, gy = 0, best = 0;
    float tcx = 0.f, tcy = 0.f, tww = 0.f, thh = 0.f;
    if (tid < NT) {
      const float* bx = boxes + ((size_t)b * NT + tid) * 4;
      float ffs = (float)fs;
      float tbx = bx[0] * ffs;
      float tby = bx[1] * ffs;
      float tw = bx[2] * ffs;
      float th = bx[3] * ffs;
      float bestr = -1.0f;
      for (int a = 0; a < 3; ++a) {
        float aw = c_aw[scale][a], ah = c_ah[scale][a];
        float inter = fminf(tw, aw) * fminf(th, ah);
        float uni = tw * th + aw * ah - inter;
        float rr = inter / (uni + 1e-6f);
        if (rr > bestr) { bestr = rr; best = a; }
      }
      gx = (int)tbx;
      if (gx < 0) gx = 0;
      if (gx > fs - 1) gx = fs - 1;
      gy = (int)tby;
      if (gy < 0) gy = 0;
      if (gy > fs - 1) gy = fs - 1;
      cell = (gy * fs + gx) * 3 + best;
      tcx = tbx - (float)gx;
      tcy = tby - (float)gy;
      tww = __logf(tw / c_aw[scale][best] + 1e-6f);
      thh = __logf(th / c_ah[scale][best] + 1e-6f);
      s_cell[tid] = cell;
      s_bit[tid] = 1u << cls[(size_t)b * NT + tid];
    }
    __syncthreads();
    if (tid < NT) {
      // last target with my cell wins; class bits union over all matches
      int win = -1;
      unsigned mask = 0u;
      for (int t = 0; t < NT; ++t)
        if (s_cell[t] == cell) { win = t; mask |= s_bit[t]; }
      if (win == tid) {
        const float* p = plane + cell * 25;
        float aw = c_aw[scale][best], ah = c_ah[scale][best];
        float d0 = sigmoid_f(p[0]) + (float)gx - tcx;
        float d1 = sigmoid_f(p[1]) + (float)gy - tcy;
        float d2 = __expf(p[2]) * aw - tww;
        float d3 = __expf(p[3]) * ah - thh;
        float coord = 5.0f * invN * (d0 * d0 + d1 * d1 + d2 * d2 + d3 * d3);
        float v4 = p[4];
        // add obj conf term, remove the noobj term the stream counted
        float conf = invN * softplus_f(-v4) - 0.5f * invN * softplus_f(v4);
        float csum = 0.0f;
        for (int c = 0; c < NC; ++c) {
          float v = p[5 + c];
          csum += ((mask >> c) & 1u) ? softplus_f(-v) : softplus_f(v);
        }
        acc = (coord + conf + csum * invNC) * (1.0f / 3.0f);
      }
    }
  }

  // ---- block reduction -> per-block partial ----
  for (int off = 32; off > 0; off >>= 1) acc += __shfl_down(acc, off);
  if ((tid & 63) == 0) s_red[tid >> 6] = acc;
  __syncthreads();
  if (tid == 0) ws[bid] = s_red[0] + s_red[1] + s_red[2] + s_red[3];
}

__global__ __launch_bounds__(1024) void reduce_kernel(
    const float* __restrict__ ws, float* __restrict__ out) {
  __shared__ float s_red[16];
  int tid = threadIdx.x;
  float v = 0.0f;
#pragma unroll
  for (int k = 0; k < 3; ++k) {
    int i = tid + k * 1024;
    if (i < NBLK) v += ws[i];
  }
  for (int off = 32; off > 0; off >>= 1) v += __shfl_down(v, off);
  if ((tid & 63) == 0) s_red[tid >> 6] = v;
  __syncthreads();
  if (tid == 0) {
    float s = 0.0f;
#pragma unroll
    for (int i = 0; i < 16; ++i) s += s_red[i];
    out[0] = s;
  }
}

extern "C" void kernel_launch(void* const* d_in, const int* in_sizes, int n_in,
                              void* d_out, int out_size, void* d_ws, size_t ws_size,
                              hipStream_t stream) {
  const float* pred0 = (const float*)d_in[0];
  const float* pred1 = (const float*)d_in[1];
  const float* pred2 = (const float*)d_in[2];
  const float* boxes = (const float*)d_in[3];
  const int* cls = (const int*)d_in[4];
  float* out = (float*)d_out;
  float* ws = (float*)d_ws;

  yolo_main<<<NBLK, 256, 0, stream>>>(pred0, pred1, pred2, boxes, cls, ws);
  reduce_kernel<<<1, 1024, 0, stream>>>(ws, out);
}

// Round 12
// 20.827 us; speedup vs baseline: 3.7153x; 1.8463x over previous
//
#include <hip/hip_runtime.h>
#include <math.h>

#define NT 50
#define NC 20
#define NB 64
#define NCORR 192                  // 3 scales x 64 batches, dispatched FIRST
#define CHUNK 2048                 // float4 per stream block (8 per thread)
#define NS0 1585                   // ceil(3244800/2048)
#define NS1 397                    // ceil(811200/2048)
#define NS2 100                    // ceil(202800/2048)
#define NSTREAM (NS0 + NS1 + NS2)  // 2082
#define NBLK (NCORR + NSTREAM)     // 2274

// anchors / stride per scale: scale0 fs=52 (masks 6,7,8), scale1 fs=26, scale2 fs=13
__device__ __constant__ float c_aw[3][3] = {
    {14.5f, 19.5f, 46.625f},
    {1.875f, 3.875f, 3.6875f},
    {0.3125f, 0.5f, 1.03125f}};
__device__ __constant__ float c_ah[3][3] = {
    {11.25f, 24.75f, 40.75f},
    {3.8125f, 2.8125f, 7.4375f},
    {0.40625f, 0.9375f, 0.71875f}};
// 1/(NB*cells) per scale: cells = 8112, 2028, 507
__device__ __constant__ float c_invN[3] = {
    1.0f / 519168.0f, 1.0f / 129792.0f, 1.0f / 32448.0f};

__device__ __forceinline__ float softplus_f(float x) {
  return __logf(1.0f + __expf(x));  // -log(1-sigmoid(x)) == softplus(x)
}
__device__ __forceinline__ float sigmoid_f(float x) {
  return 1.0f / (1.0f + __expf(-x));
}

__global__ __launch_bounds__(256) void yolo_main(
    const float* __restrict__ pred0, const float* __restrict__ pred1,
    const float* __restrict__ pred2, const float* __restrict__ boxes,
    const int* __restrict__ cls, float* __restrict__ ws) {
  const int bid = blockIdx.x;
  const int tid = threadIdx.x;
  __shared__ float s_red[4];
  float acc = 0.0f;

  if (bid >= NCORR) {
    // ---------------- STREAM: every element treated as noobj ----------------
    // Only channel f%25==4 (conf) contributes: 0.5*invN*softplus(v).
    int sb = bid - NCORR;
    int scale, part, nf4;
    const float* arr;
    if (sb < NS0) { scale = 0; part = sb; arr = pred0; nf4 = 3244800; }
    else if (sb < NS0 + NS1) { scale = 1; part = sb - NS0; arr = pred1; nf4 = 811200; }
    else { scale = 2; part = sb - NS0 - NS1; arr = pred2; nf4 = 202800; }
    const float4* p4 = (const float4*)arr;
    const int base = part * CHUNK;
    const int i0 = base + tid;
    int ch = (i0 << 2) % 25;  // channel of component .x; advance -1 mod 25 per 256 f4
    if (base + CHUNK <= nf4) {
      // full chunk: 8 independent loads in flight per thread (interleaved,
      // compiler-scheduled — do NOT stage into a local array, it spills)
#pragma unroll
      for (int k = 0; k < 8; ++k) {
        float4 v = p4[i0 + k * 256];
        float vc = (ch == 4) ? v.x : ((ch == 3) ? v.y : ((ch == 2) ? v.z : v.w));
        acc += (ch >= 1 && ch <= 4) ? softplus_f(vc) : 0.0f;
        ch = (ch >= 1) ? (ch - 1) : 24;
      }
    } else {
      for (int i = i0; i < nf4; i += 256) {
        float4 v = p4[i];
        float vc = (ch == 4) ? v.x : ((ch == 3) ? v.y : ((ch == 2) ? v.z : v.w));
        acc += (ch >= 1 && ch <= 4) ? softplus_f(vc) : 0.0f;
        ch = (ch >= 1) ? (ch - 1) : 24;
      }
    }
    acc *= c_invN[scale] * (0.5f / 3.0f);
  } else {
    // -------------- CORRECTION: exact obj-cell terms, minus over-count -----
    const int scale = bid >> 6;  // 0..2
    const int b = bid & 63;
    const int fs = (scale == 0) ? 52 : ((scale == 1) ? 26 : 13);
    const int cells = fs * fs * 3;
    const float* arr = (scale == 0) ? pred0 : ((scale == 1) ? pred1 : pred2);
    const float* plane = arr + (size_t)b * cells * 25;
    const float invN = c_invN[scale];
    const float invNC = invN * (1.0f / (float)NC);

    __shared__ int s_cell[NT];
    __shared__ unsigned s_bit[NT];

    int cell = -1, gx = 0, gy = 0, best = 0;
    float tcx = 0.f, tcy = 0.f, tww = 0.f, thh = 0.f;
    if (tid < NT) {
      const float* bx = boxes + ((size_t)b * NT + tid) * 4;
      float ffs = (float)fs;
      float tbx = bx[0] * ffs;
      float tby = bx[1] * ffs;
      float tw = bx[2] * ffs;
      float th = bx[3] * ffs;
      float bestr = -1.0f;
      for (int a = 0; a < 3; ++a) {
        float aw = c_aw[scale][a], ah = c_ah[scale][a];
        float inter = fminf(tw, aw) * fminf(th, ah);
        float uni = tw * th + aw * ah - inter;
        float rr = inter / (uni + 1e-6f);
        if (rr > bestr) { bestr = rr; best = a; }
      }
      gx = (int)tbx;
      if (gx < 0) gx = 0;
      if (gx > fs - 1) gx = fs - 1;
      gy = (int)tby;
      if (gy < 0) gy = 0;
      if (gy > fs - 1) gy = fs - 1;
      cell = (gy * fs + gx) * 3 + best;
      tcx = tbx - (float)gx;
      tcy = tby - (float)gy;
      tww = __logf(tw / c_aw[scale][best] + 1e-6f);
      thh = __logf(th / c_ah[scale][best] + 1e-6f);
      s_cell[tid] = cell;
      s_bit[tid] = 1u << cls[(size_t)b * NT + tid];
    }
    __syncthreads();
    if (tid < NT) {
      // last target with my cell wins; class bits union over all matches
      int win = -1;
      unsigned mask = 0u;
      for (int t = 0; t < NT; ++t)
        if (s_cell[t] == cell) { win = t; mask |= s_bit[t]; }
      if (win == tid) {
        const float* p = plane + cell * 25;
        float aw = c_aw[scale][best], ah = c_ah[scale][best];
        float d0 = sigmoid_f(p[0]) + (float)gx - tcx;
        float d1 = sigmoid_f(p[1]) + (float)gy - tcy;
        float d2 = __expf(p[2]) * aw - tww;
        float d3 = __expf(p[3]) * ah - thh;
        float coord = 5.0f * invN * (d0 * d0 + d1 * d1 + d2 * d2 + d3 * d3);
        float v4 = p[4];
        // add obj conf term, remove the noobj term the stream counted
        float conf = invN * softplus_f(-v4) - 0.5f * invN * softplus_f(v4);
        float csum = 0.0f;
        for (int c = 0; c < NC; ++c) {
          float v = p[5 + c];
          csum += ((mask >> c) & 1u) ? softplus_f(-v) : softplus_f(v);
        }
        acc = (coord + conf + csum * invNC) * (1.0f / 3.0f);
      }
    }
  }

  // ---- block reduction -> per-block partial ----
  for (int off = 32; off > 0; off >>= 1) acc += __shfl_down(acc, off);
  if ((tid & 63) == 0) s_red[tid >> 6] = acc;
  __syncthreads();
  if (tid == 0) ws[bid] = s_red[0] + s_red[1] + s_red[2] + s_red[3];
}

__global__ __launch_bounds__(1024) void reduce_kernel(
    const float* __restrict__ ws, float* __restrict__ out) {
  __shared__ float s_red[16];
  int tid = threadIdx.x;
  float v = 0.0f;
  for (int i = tid; i < NBLK; i += 1024) v += ws[i];
  for (int off = 32; off > 0; off >>= 1) v += __shfl_down(v, off);
  if ((tid & 63) == 0) s_red[tid >> 6] = v;
  __syncthreads();
  if (tid == 0) {
    float s = 0.0f;
#pragma unroll
    for (int i = 0; i < 16; ++i) s += s_red[i];
    out[0] = s;
  }
}

extern "C" void kernel_launch(void* const* d_in, const int* in_sizes, int n_in,
                              void* d_out, int out_size, void* d_ws, size_t ws_size,
                              hipStream_t stream) {
  const float* pred0 = (const float*)d_in[0];
  const float* pred1 = (const float*)d_in[1];
  const float* pred2 = (const float*)d_in[2];
  const float* boxes = (const float*)d_in[3];
  const int* cls = (const int*)d_in[4];
  float* out = (float*)d_out;
  float* ws = (float*)d_ws;

  yolo_main<<<NBLK, 256, 0, stream>>>(pred0, pred1, pred2, boxes, cls, ws);
  reduce_kernel<<<1, 1024, 0, stream>>>(ws, out);
}

// Round 13
// 18.863 us; speedup vs baseline: 4.1022x; 1.1041x over previous
//
#include <hip/hip_runtime.h>
#include <math.h>

#define NT 50
#define NC 20
#define NB 64
#define NCORR 192                  // 3 scales x 64 batches, dispatched FIRST
#define CPB 512                    // cells per stream block (2 per thread)
#define NS0 1014                   // 519168/512 exact
#define NS1 254                    // 253 full + 256-cell tail
#define NS2 64                     // 63 full + 192-cell tail
#define NSTREAM (NS0 + NS1 + NS2)  // 1332
#define NBLK (NCORR + NSTREAM)     // 1524

// anchors / stride per scale: scale0 fs=52 (masks 6,7,8), scale1 fs=26, scale2 fs=13
__device__ __constant__ float c_aw[3][3] = {
    {14.5f, 19.5f, 46.625f},
    {1.875f, 3.875f, 3.6875f},
    {0.3125f, 0.5f, 1.03125f}};
__device__ __constant__ float c_ah[3][3] = {
    {11.25f, 24.75f, 40.75f},
    {3.8125f, 2.8125f, 7.4375f},
    {0.40625f, 0.9375f, 0.71875f}};
// 1/(NB*cells_per_batch) per scale: cells = 8112, 2028, 507
__device__ __constant__ float c_invN[3] = {
    1.0f / 519168.0f, 1.0f / 129792.0f, 1.0f / 32448.0f};

__device__ __forceinline__ float softplus_f(float x) {
  return __logf(1.0f + __expf(x));  // -log(1-sigmoid(x)) == softplus(x)
}
__device__ __forceinline__ float sigmoid_f(float x) {
  return 1.0f / (1.0f + __expf(-x));
}

__global__ __launch_bounds__(256) void yolo_main(
    const float* __restrict__ pred0, const float* __restrict__ pred1,
    const float* __restrict__ pred2, const float* __restrict__ boxes,
    const int* __restrict__ cls, float* __restrict__ ws) {
  const int bid = blockIdx.x;
  const int tid = threadIdx.x;
  __shared__ float s_red[4];
  float acc = 0.0f;

  if (bid >= NCORR) {
    // ------------- STREAM: conf-channel gather (noobj term for ALL cells) ---
    // Only conf (float 25c+4, 1 per 100B) contributes: 0.5*invN*softplus(v).
    // Gather touches 16 of every 25 64B-lines instead of all of them.
    int sb = bid - NCORR;
    int scale, ncell;
    const float* arr;
    if (sb < NS0) { scale = 0; arr = pred0; ncell = 519168; }
    else if (sb < NS0 + NS1) { scale = 1; arr = pred1; ncell = 129792; sb -= NS0; }
    else { scale = 2; arr = pred2; ncell = 32448; sb -= NS0 + NS1; }
    const int c0 = sb * CPB + tid;
    const int c1 = c0 + 256;
    // two independent gather loads in flight
    float a0 = 0.0f, a1 = 0.0f;
    if (c0 < ncell) a0 = softplus_f(arr[25 * c0 + 4]);
    if (c1 < ncell) a1 = softplus_f(arr[25 * c1 + 4]);
    acc = (a0 + a1) * (c_invN[scale] * (0.5f / 3.0f));
  } else {
    // -------------- CORRECTION: exact obj-cell terms, minus over-count -----
    const int scale = bid >> 6;  // 0..2
    const int b = bid & 63;
    const int fs = (scale == 0) ? 52 : ((scale == 1) ? 26 : 13);
    const int cells = fs * fs * 3;
    const float* arr = (scale == 0) ? pred0 : ((scale == 1) ? pred1 : pred2);
    const float* plane = arr + (size_t)b * cells * 25;
    const float invN = c_invN[scale];
    const float invNC = invN * (1.0f / (float)NC);

    __shared__ int s_cell[NT];
    __shared__ unsigned s_bit[NT];

    int cell = -1, gx = 0, gy = 0, best = 0;
    float tcx = 0.f, tcy = 0.f, tww = 0.f, thh = 0.f;
    if (tid < NT) {
      const float* bx = boxes + ((size_t)b * NT + tid) * 4;
      float ffs = (float)fs;
      float tbx = bx[0] * ffs;
      float tby = bx[1] * ffs;
      float tw = bx[2] * ffs;
      float th = bx[3] * ffs;
      float bestr = -1.0f;
      for (int a = 0; a < 3; ++a) {
        float aw = c_aw[scale][a], ah = c_ah[scale][a];
        float inter = fminf(tw, aw) * fminf(th, ah);
        float uni = tw * th + aw * ah - inter;
        float rr = inter / (uni + 1e-6f);
        if (rr > bestr) { bestr = rr; best = a; }
      }
      gx = (int)tbx;
      if (gx < 0) gx = 0;
      if (gx > fs - 1) gx = fs - 1;
      gy = (int)tby;
      if (gy < 0) gy = 0;
      if (gy > fs - 1) gy = fs - 1;
      cell = (gy * fs + gx) * 3 + best;
      tcx = tbx - (float)gx;
      tcy = tby - (float)gy;
      tww = __logf(tw / c_aw[scale][best] + 1e-6f);
      thh = __logf(th / c_ah[scale][best] + 1e-6f);
      s_cell[tid] = cell;
      s_bit[tid] = 1u << cls[(size_t)b * NT + tid];
    }
    __syncthreads();
    if (tid < NT) {
      // last target with my cell wins; class bits union over all matches
      int win = -1;
      unsigned mask = 0u;
      for (int t = 0; t < NT; ++t)
        if (s_cell[t] == cell) { win = t; mask |= s_bit[t]; }
      if (win == tid) {
        const float* p = plane + cell * 25;
        float aw = c_aw[scale][best], ah = c_ah[scale][best];
        float d0 = sigmoid_f(p[0]) + (float)gx - tcx;
        float d1 = sigmoid_f(p[1]) + (float)gy - tcy;
        float d2 = __expf(p[2]) * aw - tww;
        float d3 = __expf(p[3]) * ah - thh;
        float coord = 5.0f * invN * (d0 * d0 + d1 * d1 + d2 * d2 + d3 * d3);
        float v4 = p[4];
        // add obj conf term, remove the noobj term the stream counted
        float conf = invN * softplus_f(-v4) - 0.5f * invN * softplus_f(v4);
        float csum = 0.0f;
        for (int c = 0; c < NC; ++c) {
          float v = p[5 + c];
          csum += ((mask >> c) & 1u) ? softplus_f(-v) : softplus_f(v);
        }
        acc = (coord + conf + csum * invNC) * (1.0f / 3.0f);
      }
    }
  }

  // ---- block reduction -> per-block partial ----
  for (int off = 32; off > 0; off >>= 1) acc += __shfl_down(acc, off);
  if ((tid & 63) == 0) s_red[tid >> 6] = acc;
  __syncthreads();
  if (tid == 0) ws[bid] = s_red[0] + s_red[1] + s_red[2] + s_red[3];
}

__global__ __launch_bounds__(1024) void reduce_kernel(
    const float* __restrict__ ws, float* __restrict__ out) {
  __shared__ float s_red[16];
  int tid = threadIdx.x;
  float v = 0.0f;
  for (int i = tid; i < NBLK; i += 1024) v += ws[i];
  for (int off = 32; off > 0; off >>= 1) v += __shfl_down(v, off);
  if ((tid & 63) == 0) s_red[tid >> 6] = v;
  __syncthreads();
  if (tid == 0) {
    float s = 0.0f;
#pragma unroll
    for (int i = 0; i < 16; ++i) s += s_red[i];
    out[0] = s;
  }
}

extern "C" void kernel_launch(void* const* d_in, const int* in_sizes, int n_in,
                              void* d_out, int out_size, void* d_ws, size_t ws_size,
                              hipStream_t stream) {
  const float* pred0 = (const float*)d_in[0];
  const float* pred1 = (const float*)d_in[1];
  const float* pred2 = (const float*)d_in[2];
  const float* boxes = (const float*)d_in[3];
  const int* cls = (const int*)d_in[4];
  float* out = (float*)d_out;
  float* ws = (float*)d_ws;

  yolo_main<<<NBLK, 256, 0, stream>>>(pred0, pred1, pred2, boxes, cls, ws);
  reduce_kernel<<<1, 1024, 0, stream>>>(ws, out);
}

// Round 14
// 17.931 us; speedup vs baseline: 4.3152x; 1.0519x over previous
//
#include <hip/hip_runtime.h>
#include <math.h>

#define NT 50
#define NC 20
#define NB 64
#define NCORR 192                  // 3 scales x 64 batches, dispatched FIRST
#define CPB 1024                   // cells per stream block (4 per thread)
#define NS0 507                    // 519168/1024 exact
#define NS1 127                    // 126 full + tail
#define NS2 32                     // 31 full + tail
#define NSTREAM (NS0 + NS1 + NS2)  // 666
#define NBLK (NCORR + NSTREAM)     // 858

// anchors / stride per scale: scale0 fs=52 (masks 6,7,8), scale1 fs=26, scale2 fs=13
__device__ __constant__ float c_aw[3][3] = {
    {14.5f, 19.5f, 46.625f},
    {1.875f, 3.875f, 3.6875f},
    {0.3125f, 0.5f, 1.03125f}};
__device__ __constant__ float c_ah[3][3] = {
    {11.25f, 24.75f, 40.75f},
    {3.8125f, 2.8125f, 7.4375f},
    {0.40625f, 0.9375f, 0.71875f}};
// 1/(NB*cells_per_batch) per scale: cells = 8112, 2028, 507
__device__ __constant__ float c_invN[3] = {
    1.0f / 519168.0f, 1.0f / 129792.0f, 1.0f / 32448.0f};

__device__ __forceinline__ float softplus_f(float x) {
  return __logf(1.0f + __expf(x));  // -log(1-sigmoid(x)) == softplus(x)
}
__device__ __forceinline__ float sigmoid_f(float x) {
  return 1.0f / (1.0f + __expf(-x));
}

__global__ __launch_bounds__(256) void yolo_main(
    const float* __restrict__ pred0, const float* __restrict__ pred1,
    const float* __restrict__ pred2, const float* __restrict__ boxes,
    const int* __restrict__ cls, float* __restrict__ ws) {
  const int bid = blockIdx.x;
  const int tid = threadIdx.x;
  __shared__ float s_red[4];
  float acc = 0.0f;

  if (bid >= NCORR) {
    // ------------- STREAM: conf-channel gather (noobj term for ALL cells) ---
    // Only conf (float 25c+4, 1 per 100B) contributes: 0.5*invN*softplus(v).
    // 4 interleaved gather loads per thread (use-immediately: no staging
    // array -> no scratch demotion, compiler keeps loads in flight).
    int sb = bid - NCORR;
    int scale, ncell;
    const float* arr;
    if (sb < NS0) { scale = 0; arr = pred0; ncell = 519168; }
    else if (sb < NS0 + NS1) { scale = 1; arr = pred1; ncell = 129792; sb -= NS0; }
    else { scale = 2; arr = pred2; ncell = 32448; sb -= NS0 + NS1; }
    const int c0 = sb * CPB + tid;
#pragma unroll
    for (int k = 0; k < 4; ++k) {
      int c = c0 + k * 256;
      if (c < ncell) acc += softplus_f(arr[25 * c + 4]);
    }
    acc *= c_invN[scale] * (0.5f / 3.0f);
  } else {
    // -------------- CORRECTION: exact obj-cell terms, minus over-count -----
    const int scale = bid >> 6;  // 0..2
    const int b = bid & 63;
    const int fs = (scale == 0) ? 52 : ((scale == 1) ? 26 : 13);
    const int cells = fs * fs * 3;
    const float* arr = (scale == 0) ? pred0 : ((scale == 1) ? pred1 : pred2);
    const float* plane = arr + (size_t)b * cells * 25;
    const float invN = c_invN[scale];
    const float invNC = invN * (1.0f / (float)NC);

    __shared__ int s_cell[NT];
    __shared__ unsigned s_bit[NT];

    int cell = -1, gx = 0, gy = 0, best = 0;
    float tcx = 0.f, tcy = 0.f, tww = 0.f, thh = 0.f;
    if (tid < NT) {
      const float* bx = boxes + ((size_t)b * NT + tid) * 4;
      float ffs = (float)fs;
      float tbx = bx[0] * ffs;
      float tby = bx[1] * ffs;
      float tw = bx[2] * ffs;
      float th = bx[3] * ffs;
      float bestr = -1.0f;
      for (int a = 0; a < 3; ++a) {
        float aw = c_aw[scale][a], ah = c_ah[scale][a];
        float inter = fminf(tw, aw) * fminf(th, ah);
        float uni = tw * th + aw * ah - inter;
        float rr = inter / (uni + 1e-6f);
        if (rr > bestr) { bestr = rr; best = a; }
      }
      gx = (int)tbx;
      if (gx < 0) gx = 0;
      if (gx > fs - 1) gx = fs - 1;
      gy = (int)tby;
      if (gy < 0) gy = 0;
      if (gy > fs - 1) gy = fs - 1;
      cell = (gy * fs + gx) * 3 + best;
      tcx = tbx - (float)gx;
      tcy = tby - (float)gy;
      tww = __logf(tw / c_aw[scale][best] + 1e-6f);
      thh = __logf(th / c_ah[scale][best] + 1e-6f);
      s_cell[tid] = cell;
      s_bit[tid] = 1u << cls[(size_t)b * NT + tid];
    }
    __syncthreads();
    if (tid < NT) {
      // last target with my cell wins; class bits union over all matches
      int win = -1;
      unsigned mask = 0u;
      for (int t = 0; t < NT; ++t)
        if (s_cell[t] == cell) { win = t; mask |= s_bit[t]; }
      if (win == tid) {
        const float* p = plane + cell * 25;
        float aw = c_aw[scale][best], ah = c_ah[scale][best];
        float d0 = sigmoid_f(p[0]) + (float)gx - tcx;
        float d1 = sigmoid_f(p[1]) + (float)gy - tcy;
        float d2 = __expf(p[2]) * aw - tww;
        float d3 = __expf(p[3]) * ah - thh;
        float coord = 5.0f * invN * (d0 * d0 + d1 * d1 + d2 * d2 + d3 * d3);
        float v4 = p[4];
        // add obj conf term, remove the noobj term the stream counted
        float conf = invN * softplus_f(-v4) - 0.5f * invN * softplus_f(v4);
        float csum = 0.0f;
        for (int c = 0; c < NC; ++c) {
          float v = p[5 + c];
          csum += ((mask >> c) & 1u) ? softplus_f(-v) : softplus_f(v);
        }
        acc = (coord + conf + csum * invNC) * (1.0f / 3.0f);
      }
    }
  }

  // ---- block reduction -> per-block partial ----
  for (int off = 32; off > 0; off >>= 1) acc += __shfl_down(acc, off);
  if ((tid & 63) == 0) s_red[tid >> 6] = acc;
  __syncthreads();
  if (tid == 0) ws[bid] = s_red[0] + s_red[1] + s_red[2] + s_red[3];
}

__global__ __launch_bounds__(1024) void reduce_kernel(
    const float* __restrict__ ws, float* __restrict__ out) {
  __shared__ float s_red[16];
  int tid = threadIdx.x;
  float v = (tid < NBLK) ? ws[tid] : 0.0f;  // single round: NBLK <= 1024
  for (int off = 32; off > 0; off >>= 1) v += __shfl_down(v, off);
  if ((tid & 63) == 0) s_red[tid >> 6] = v;
  __syncthreads();
  if (tid == 0) {
    float s = 0.0f;
#pragma unroll
    for (int i = 0; i < 16; ++i) s += s_red[i];
    out[0] = s;
  }
}

extern "C" void kernel_launch(void* const* d_in, const int* in_sizes, int n_in,
                              void* d_out, int out_size, void* d_ws, size_t ws_size,
                              hipStream_t stream) {
  const float* pred0 = (const float*)d_in[0];
  const float* pred1 = (const float*)d_in[1];
  const float* pred2 = (const float*)d_in[2];
  const float* boxes = (const float*)d_in[3];
  const int* cls = (const int*)d_in[4];
  float* out = (float*)d_out;
  float* ws = (float*)d_ws;

  yolo_main<<<NBLK, 256, 0, stream>>>(pred0, pred1, pred2, boxes, cls, ws);
  reduce_kernel<<<1, 1024, 0, stream>>>(ws, out);
}

// Round 15
// 17.304 us; speedup vs baseline: 4.4715x; 1.0362x over previous
//
#include <hip/hip_runtime.h>
#include <math.h>

#define NT 50
#define NC 20
#define NB 64
#define NCORR 192                  // 3 scales x 64 batches, dispatched FIRST
#define CPB 1536                   // cells per stream block (6 per thread)
#define NS0 338                    // 519168/1536 exact
#define NS1 85                     // 84 full + 768-cell tail
#define NS2 22                     // 21 full + 192-cell tail
#define NSTREAM (NS0 + NS1 + NS2)  // 445
#define NBLK (NCORR + NSTREAM)     // 637

// anchors / stride per scale: scale0 fs=52 (masks 6,7,8), scale1 fs=26, scale2 fs=13
__device__ __constant__ float c_aw[3][3] = {
    {14.5f, 19.5f, 46.625f},
    {1.875f, 3.875f, 3.6875f},
    {0.3125f, 0.5f, 1.03125f}};
__device__ __constant__ float c_ah[3][3] = {
    {11.25f, 24.75f, 40.75f},
    {3.8125f, 2.8125f, 7.4375f},
    {0.40625f, 0.9375f, 0.71875f}};
// 1/(NB*cells_per_batch) per scale: cells = 8112, 2028, 507
__device__ __constant__ float c_invN[3] = {
    1.0f / 519168.0f, 1.0f / 129792.0f, 1.0f / 32448.0f};

__device__ __forceinline__ float softplus_f(float x) {
  return __logf(1.0f + __expf(x));  // -log(1-sigmoid(x)) == softplus(x)
}
__device__ __forceinline__ float sigmoid_f(float x) {
  return 1.0f / (1.0f + __expf(-x));
}

__global__ __launch_bounds__(256) void yolo_main(
    const float* __restrict__ pred0, const float* __restrict__ pred1,
    const float* __restrict__ pred2, const float* __restrict__ boxes,
    const int* __restrict__ cls, float* __restrict__ ws) {
  const int bid = blockIdx.x;
  const int tid = threadIdx.x;
  __shared__ float s_red[4];
  float acc = 0.0f;

  if (bid >= NCORR) {
    // ------------- STREAM: conf-channel gather (noobj term for ALL cells) ---
    // Only conf (float 25c+4, 1 per 100B) contributes: 0.5*invN*softplus(v).
    // 6 interleaved gather loads per thread (use-immediately: no staging
    // array -> no scratch demotion; compiler keeps loads in flight).
    int sb = bid - NCORR;
    int scale, ncell;
    const float* arr;
    if (sb < NS0) { scale = 0; arr = pred0; ncell = 519168; }
    else if (sb < NS0 + NS1) { scale = 1; arr = pred1; ncell = 129792; sb -= NS0; }
    else { scale = 2; arr = pred2; ncell = 32448; sb -= NS0 + NS1; }
    const int c0 = sb * CPB + tid;
#pragma unroll
    for (int k = 0; k < 6; ++k) {
      int c = c0 + k * 256;
      if (c < ncell) acc += softplus_f(arr[25 * c + 4]);
    }
    acc *= c_invN[scale] * (0.5f / 3.0f);
  } else {
    // -------------- CORRECTION: exact obj-cell terms, minus over-count -----
    const int scale = bid >> 6;  // 0..2
    const int b = bid & 63;
    const int fs = (scale == 0) ? 52 : ((scale == 1) ? 26 : 13);
    const int cells = fs * fs * 3;
    const float* arr = (scale == 0) ? pred0 : ((scale == 1) ? pred1 : pred2);
    const float* plane = arr + (size_t)b * cells * 25;
    const float invN = c_invN[scale];
    const float invNC = invN * (1.0f / (float)NC);

    __shared__ int s_cell[NT];
    __shared__ unsigned s_bit[NT];

    int cell = -1, gx = 0, gy = 0, best = 0;
    float tcx = 0.f, tcy = 0.f, tww = 0.f, thh = 0.f;
    if (tid < NT) {
      const float* bx = boxes + ((size_t)b * NT + tid) * 4;
      float ffs = (float)fs;
      float tbx = bx[0] * ffs;
      float tby = bx[1] * ffs;
      float tw = bx[2] * ffs;
      float th = bx[3] * ffs;
      float bestr = -1.0f;
      for (int a = 0; a < 3; ++a) {
        float aw = c_aw[scale][a], ah = c_ah[scale][a];
        float inter = fminf(tw, aw) * fminf(th, ah);
        float uni = tw * th + aw * ah - inter;
        float rr = inter / (uni + 1e-6f);
        if (rr > bestr) { bestr = rr; best = a; }
      }
      gx = (int)tbx;
      if (gx < 0) gx = 0;
      if (gx > fs - 1) gx = fs - 1;
      gy = (int)tby;
      if (gy < 0) gy = 0;
      if (gy > fs - 1) gy = fs - 1;
      cell = (gy * fs + gx) * 3 + best;
      tcx = tbx - (float)gx;
      tcy = tby - (float)gy;
      tww = __logf(tw / c_aw[scale][best] + 1e-6f);
      thh = __logf(th / c_ah[scale][best] + 1e-6f);
      s_cell[tid] = cell;
      s_bit[tid] = 1u << cls[(size_t)b * NT + tid];
    }
    __syncthreads();
    if (tid < NT) {
      // last target with my cell wins; class bits union over all matches
      int win = -1;
      unsigned mask = 0u;
      for (int t = 0; t < NT; ++t)
        if (s_cell[t] == cell) { win = t; mask |= s_bit[t]; }
      if (win == tid) {
        const float* p = plane + cell * 25;
        float aw = c_aw[scale][best], ah = c_ah[scale][best];
        float d0 = sigmoid_f(p[0]) + (float)gx - tcx;
        float d1 = sigmoid_f(p[1]) + (float)gy - tcy;
        float d2 = __expf(p[2]) * aw - tww;
        float d3 = __expf(p[3]) * ah - thh;
        float coord = 5.0f * invN * (d0 * d0 + d1 * d1 + d2 * d2 + d3 * d3);
        float v4 = p[4];
        // add obj conf term, remove the noobj term the stream counted
        float conf = invN * softplus_f(-v4) - 0.5f * invN * softplus_f(v4);
        float csum = 0.0f;
        for (int c = 0; c < NC; ++c) {
          float v = p[5 + c];
          csum += ((mask >> c) & 1u) ? softplus_f(-v) : softplus_f(v);
        }
        acc = (coord + conf + csum * invNC) * (1.0f / 3.0f);
      }
    }
  }

  // ---- block reduction -> per-block partial ----
  for (int off = 32; off > 0; off >>= 1) acc += __shfl_down(acc, off);
  if ((tid & 63) == 0) s_red[tid >> 6] = acc;
  __syncthreads();
  if (tid == 0) ws[bid] = s_red[0] + s_red[1] + s_red[2] + s_red[3];
}

__global__ __launch_bounds__(1024) void reduce_kernel(
    const float* __restrict__ ws, float* __restrict__ out) {
  __shared__ float s_red[16];
  int tid = threadIdx.x;
  float v = (tid < NBLK) ? ws[tid] : 0.0f;  // single round: NBLK <= 1024
  for (int off = 32; off > 0; off >>= 1) v += __shfl_down(v, off);
  if ((tid & 63) == 0) s_red[tid >> 6] = v;
  __syncthreads();
  if (tid == 0) {
    float s = 0.0f;
#pragma unroll
    for (int i = 0; i < 16; ++i) s += s_red[i];
    out[0] = s;
  }
}

extern "C" void kernel_launch(void* const* d_in, const int* in_sizes, int n_in,
                              void* d_out, int out_size, void* d_ws, size_t ws_size,
                              hipStream_t stream) {
  const float* pred0 = (const float*)d_in[0];
  const float* pred1 = (const float*)d_in[1];
  const float* pred2 = (const float*)d_in[2];
  const float* boxes = (const float*)d_in[3];
  const int* cls = (const int*)d_in[4];
  float* out = (float*)d_out;
  float* ws = (float*)d_ws;

  yolo_main<<<NBLK, 256, 0, stream>>>(pred0, pred1, pred2, boxes, cls, ws);
  reduce_kernel<<<1, 1024, 0, stream>>>(ws, out);
}